// Round 10
// baseline (143.399 us; speedup 1.0000x reference)
//
#include <hip/hip_runtime.h>
#include <math.h>

#define HH 4096
#define WW 4096
#define WPR 64                  // 64-bit words per row
#define NWORDS (HH * WPR)       // 262144
typedef unsigned long long u64;
typedef float f32x4 __attribute__((ext_vector_type(4)));   // nontemporal-capable

#define TILE_R 128              // interior rows per block
#define HALO_R 60               // vertical halo (= #half-sweeps)
#define REG_R  248              // TILE_R + 2*HALO_R
#define REG_WC 10               // 8 interior word-cols + 1 halo each side
#define RWORDS (REG_R * REG_WC) // 2480
#define NTHR   1024
#define WPT    3                // ceil(RWORDS / NTHR)
#define NSWEEP 60
#define PACK_WPW 16             // words per wave in pack kernel

struct C15 { float v[15]; };    // host-computed crossover seeds (device-verified)

// fp64 decision, EXACTLY as the round-1 kernel that scored absmax=0.
__device__ __forceinline__ bool decision(float p, int ncnt, int ns) {
    double pd = (double)p;
    double u1 = -log(pd + 1e-6);
    double u0 = -log1p(-(pd - 1e-6));
    double cost1 = u1 + 0.5 * (double)(ncnt - ns);
    double cost0 = u0 + 0.5 * (double)ns;
    return cost1 < cost0;
}

// Pack labels + k-planes AoS: Kp[4w+0..3] = (L, k0, k1, k2), 32B-aligned.
// Wave-0 lanes verify the host-seeded crossovers against the device
// decision() (exactness guaranteed; full on-device search as fallback).
__global__ __launch_bounds__(256)
void pack_kernel(const float* __restrict__ probs, C15 Ch,
                 u64* __restrict__ Kp) {
    __shared__ float Cs[15];
    const int tid = threadIdx.x;
    if (tid < 15) {
        int ncnt = 2 + tid / 5;
        int ns = tid % 5;
        unsigned cb = __float_as_uint(Ch.v[tid]);
        bool ok = false;
        if (cb > 0u && cb <= 0x3F800000u) {
            bool below = decision(__uint_as_float(cb - 1u), ncnt, ns);
            bool at = decision(__uint_as_float(cb), ncnt, ns);
            ok = (!below) && (at || cb == 0x3F800000u);
        }
        if (!ok) {   // host/device libm mismatch (never observed) -> exact search
            unsigned lo = 0u, hi = 0x3F800000u;
            while (hi - lo > 1u) {
                unsigned mid = lo + (hi - lo) / 2u;
                if (decision(__uint_as_float(mid), ncnt, ns)) hi = mid; else lo = mid;
            }
            cb = hi;
        }
        Cs[tid] = __uint_as_float(cb);
    }
    __syncthreads();

    int gwave = (blockIdx.x * 256 + tid) >> 6;
    int lane = tid & 63;
    int w0 = gwave * PACK_WPW;
    float p[PACK_WPW];
#pragma unroll
    for (int q = 0; q < PACK_WPW; ++q)
        p[q] = __builtin_nontemporal_load(&probs[((size_t)(w0 + q) << 6) + lane]);
    const float c0 = Cs[10], c1 = Cs[11], c2 = Cs[12], c3 = Cs[13], c4 = Cs[14];
#pragma unroll
    for (int q = 0; q < PACK_WPW; ++q) {
        int w = w0 + q;
        int i = w >> 6;                  // row
        int jbase = (w & 63) << 6;       // column of lane 0
        float pp = p[q];
        int k = (pp < c0) + (pp < c1) + (pp < c2) + (pp < c3) + (pp < c4);
        bool gE0 = (i == 0), gE1 = (i == HH - 1);
        bool jE0 = (jbase == 0) & (lane == 0);
        bool jE1 = (jbase == WW - 64) & (lane == 63);
        if (gE0 | gE1 | jE0 | jE1) {     // rare, divergent border fixup
            int ncnt = 4 - gE0 - gE1 - jE0 - jE1;
            const float* Cr = Cs + (ncnt - 2) * 5;
            k = (pp < Cr[0]) + (pp < Cr[1]) + (pp < Cr[2]) + (pp < Cr[3]) + (pp < Cr[4]);
        }
        u64 lb = __ballot(pp > 0.5f);
        u64 b0 = __ballot(k & 1);
        u64 b1 = __ballot(k & 2);
        u64 b2 = __ballot(k & 4);
        if (lane < 4) {
            u64 v = (lane == 0) ? lb : (lane == 1) ? b0 : (lane == 2) ? b1 : b2;
            Kp[4ull * w + lane] = v;
        }
    }
}

// Fused: (A) load packed region via b128 pairs (labels->LDS+regs, k-planes
// ->regs only), (B) half-sweeps with convergence early-exit, (C) expand.
__global__ __attribute__((amdgpu_flat_work_group_size(NTHR, NTHR),
                          amdgpu_waves_per_eu(4, 4)))
void fused_all(const u64* __restrict__ Kp, float* __restrict__ out) {
    __shared__ u64 SL[RWORDS];           // 19,840 B (labels only)
    __shared__ int chg[3];               // change flags, slot = sweep % 3

    const int tid = threadIdx.x;
    const int lane = tid & 63;
    const int tr = blockIdx.x >> 3;      // 0..31 tile row
    const int tc = blockIdx.x & 7;       // 0..7  tile col
    const int r0 = tr * TILE_R - HALO_R; // global row of region row 0
    const int wc0 = tc * 8 - 1;          // global word-col of region col 0

    if (tid < 3) chg[tid] = 0;

    // ---- Phase A: two ulonglong2 loads per word; k-planes in regs only ----
    const ulonglong2* Kp2 = (const ulonglong2*)Kp;
    u64 cur[WPT], k0[WPT], k1[WPT], k2[WPT], basem[WPT];
    int rr[WPT], cc[WPT];
#pragma unroll
    for (int m = 0; m < WPT; ++m) {
        int idx = tid + NTHR * m;
        int r = 0, c = 0;
        u64 l = 0, a = ~0ull, b = ~0ull, d = ~0ull;   // outside: label 0, k=7
        if (m < 2 || idx < RWORDS) {
            r = idx / REG_WC;
            c = idx - REG_WC * r;
            int g = r0 + r, wc = wc0 + c;
            if (g >= 0 && g < HH && wc >= 0 && wc < WPR) {
                size_t w = (size_t)g * WPR + wc;
                ulonglong2 x = Kp2[2 * w];       // (L, k0)
                ulonglong2 y = Kp2[2 * w + 1];   // (k1, k2)
                l = x.x; a = x.y; b = y.x; d = y.y;
            }
            SL[idx] = l;
        }
        cur[m] = l; k0[m] = a; k1[m] = b; k2[m] = d;
        rr[m] = r; cc[m] = c;
        basem[m] = ((r0 + r) & 1) ? 0xAAAAAAAAAAAAAAAAull
                                  : 0x5555555555555555ull;
    }
    __syncthreads();

    // ---- Phase B: in-place half-sweeps + convergence early-exit.
    // Two consecutive no-change half-sweeps => fixed point; later trapezoids
    // are subsets updated by the same rule -> identity -> break, bit-exact.
    // chg slots mod-3: clear of slot (s+1)%3 at sweep s is separated from its
    // last readers (sweep s-2) by the sweep-(s-1) barrier.
    int prevf = 1;
    for (int s = 0; s < NSWEEP; ++s) {
        if (tid == 0) chg[(s + 1) % 3] = 0;
        const u64 flip = (s & 1) ? ~0ull : 0ull;
        const int rlo = s + 1, rhi = REG_R - 1 - s;   // trapezoid bounds
        u64 chacc = 0;
#pragma unroll
        for (int m = 0; m < WPT; ++m) {
            int idx = tid + NTHR * m;
            int r = rr[m];
            if ((m < 2 || idx < RWORDS) && r >= rlo && r < rhi) {
                int c = cc[m];
                u64 center = cur[m];
                u64 up = SL[idx - REG_WC], dn = SL[idx + REG_WC];
                u64 pw = (c > 0) ? SL[idx - 1] : 0ull;
                u64 nw = (c < REG_WC - 1) ? SL[idx + 1] : 0ull;
                u64 lv = (center << 1) | (pw >> 63);
                u64 rv = (center >> 1) | (nw << 63);
                // bit-sliced ns = up+dn+lv+rv (planes n2:n1:n0)
                u64 sxy = up ^ dn, ca = up & dn;
                u64 txy = lv ^ rv, cb = lv & rv;
                u64 n0 = sxy ^ txy, cd = sxy & txy;
                u64 n1 = ca ^ cb ^ cd;
                u64 n2 = (ca & cb) | (cd & (ca ^ cb));
                // ge = (ns >= k), 3-bit unsigned compare
                u64 ge = (n2 & ~k2[m]) |
                         (~(n2 ^ k2[m]) & ((n1 & ~k1[m]) |
                                           (~(n1 ^ k1[m]) & (n0 | ~k0[m]))));
                u64 mask = basem[m] ^ flip;
                u64 nv = (ge & mask) | (center & ~mask);   // BFI
                chacc |= nv ^ center;
                cur[m] = nv;
                SL[idx] = nv;   // race-free: writes touch only parity-s bits
            }
        }
        if (__ballot(chacc != 0) != 0ull) {
            if (lane == 0) chg[s % 3] = 1;    // benign race, all write 1
        }
        __syncthreads();
        int curf = chg[s % 3];
        if (prevf == 0 && curf == 0) break;   // block-uniform decision
        prevf = curf;
    }

    // ---- Phase C: expand interior to float4 output (nontemporal stream) ----
#pragma unroll 4
    for (int m = 0; m < 16; ++m) {
        int idx = tid + NTHR * m;          // 0..16383 float4s
        int ri = idx >> 7;                 // interior row 0..127
        int q = idx & 127;                 // float4 within row
        u64 word = SL[(HALO_R + ri) * REG_WC + 1 + (q >> 4)];
        unsigned bits = (unsigned)(word >> ((q & 15) * 4)) & 0xFu;
        f32x4 v;
        v.x = (float)(bits & 1u);
        v.y = (float)((bits >> 1) & 1u);
        v.z = (float)((bits >> 2) & 1u);
        v.w = (float)((bits >> 3) & 1u);
        int g = tr * TILE_R + ri;
        __builtin_nontemporal_store(v,
            &((f32x4*)out)[(size_t)g * (WW / 4) + (wc0 + 1) * 16 + q]);
    }
}

// Host-side replica of the crossover computation (seed only; device verifies).
static bool h_decision(float p, int ncnt, int ns) {
    double pd = (double)p;
    double u1 = -log(pd + 1e-6);
    double u0 = -log1p(-(pd - 1e-6));
    return (u1 + 0.5 * (double)(ncnt - ns)) < (u0 + 0.5 * (double)ns);
}
static unsigned h_f2u(float f) { union { float f; unsigned u; } x; x.f = f; return x.u; }
static float h_u2f(unsigned u) { union { float f; unsigned u; } x; x.u = u; return x.f; }

extern "C" void kernel_launch(void* const* d_in, const int* in_sizes, int n_in,
                              void* d_out, int out_size, void* d_ws, size_t ws_size,
                              hipStream_t stream) {
    const float* probs = (const float*)d_in[0];
    float* out = (float*)d_out;
    u64* Kp = (u64*)d_ws;                // 8 MB AoS (L,k0,k1,k2)

    // Host: compute the 15 crossover constants (runs once at graph capture).
    C15 Ch;
    for (int t = 0; t < 15; ++t) {
        int ncnt = 2 + t / 5, ns = t % 5;
        unsigned lo = 0u, hi = 0x3F800000u;
        double T = 0.5 * (double)(2 * ns - ncnt);
        double eT = exp(T);
        double p0 = (1.0 + 1e-6 - 1e-6 * eT) / (1.0 + eT);
        float f0 = (float)p0;
        if (f0 < 0.0f) f0 = 0.0f;
        if (f0 > 1.0f) f0 = 1.0f;
        unsigned b0 = h_f2u(f0);
        unsigned l2 = (b0 > 64u) ? b0 - 64u : 0u;
        unsigned h2 = (b0 + 64u < 0x3F800000u) ? b0 + 64u : 0x3F800000u;
        if (!h_decision(h_u2f(l2), ncnt, ns)) lo = l2;
        if (h_decision(h_u2f(h2), ncnt, ns)) hi = h2;
        while (hi - lo > 1u) {
            unsigned mid = lo + (hi - lo) / 2u;
            if (h_decision(h_u2f(mid), ncnt, ns)) hi = mid; else lo = mid;
        }
        Ch.v[t] = h_u2f(hi);
    }

    pack_kernel<<<NWORDS / (PACK_WPW * 4), 256, 0, stream>>>(probs, Ch, Kp);
    fused_all<<<256, NTHR, 0, stream>>>(Kp, out);
}

// Round 11
// 135.914 us; speedup vs baseline: 1.0551x; 1.0551x over previous
//
#include <hip/hip_runtime.h>
#include <math.h>

#define HH 4096
#define WW 4096
#define WPR 64                  // 64-bit words per row
#define NWORDS (HH * WPR)       // 262144
typedef unsigned long long u64;

#define TILE_R 128              // interior rows per block
#define HALO_R 60               // vertical halo (= #half-sweeps)
#define REG_R  248              // TILE_R + 2*HALO_R
#define REG_WC 10               // 8 interior word-cols + 1 halo each side
#define RWORDS (REG_R * REG_WC) // 2480
#define NTHR   1024
#define WPT    3                // ceil(RWORDS / NTHR)
#define NSWEEP 60
#define PACK_WPW 16             // words per wave in pack kernel

struct C15 { float v[15]; };    // host-computed crossover seeds (device-verified)

// fp64 decision, EXACTLY as the round-1 kernel that scored absmax=0.
__device__ __forceinline__ bool decision(float p, int ncnt, int ns) {
    double pd = (double)p;
    double u1 = -log(pd + 1e-6);
    double u0 = -log1p(-(pd - 1e-6));
    double cost1 = u1 + 0.5 * (double)(ncnt - ns);
    double cost0 = u0 + 0.5 * (double)ns;
    return cost1 < cost0;
}

// Pack labels + k-planes AoS: Kp[4w+0..3] = (L, k0, k1, k2), 32B-aligned.
// Wave-0 lanes verify the host-seeded crossovers against the device
// decision() (exactness guaranteed; full on-device search as fallback).
__global__ __launch_bounds__(256)
void pack_kernel(const float* __restrict__ probs, C15 Ch,
                 u64* __restrict__ Kp) {
    __shared__ float Cs[15];
    const int tid = threadIdx.x;
    if (tid < 15) {
        int ncnt = 2 + tid / 5;
        int ns = tid % 5;
        unsigned cb = __float_as_uint(Ch.v[tid]);
        bool ok = false;
        if (cb > 0u && cb <= 0x3F800000u) {
            bool below = decision(__uint_as_float(cb - 1u), ncnt, ns);
            bool at = decision(__uint_as_float(cb), ncnt, ns);
            ok = (!below) && (at || cb == 0x3F800000u);
        }
        if (!ok) {   // host/device libm mismatch (never observed) -> exact search
            unsigned lo = 0u, hi = 0x3F800000u;
            while (hi - lo > 1u) {
                unsigned mid = lo + (hi - lo) / 2u;
                if (decision(__uint_as_float(mid), ncnt, ns)) hi = mid; else lo = mid;
            }
            cb = hi;
        }
        Cs[tid] = __uint_as_float(cb);
    }
    __syncthreads();

    int gwave = (blockIdx.x * 256 + tid) >> 6;
    int lane = tid & 63;
    int w0 = gwave * PACK_WPW;
    float p[PACK_WPW];
#pragma unroll
    for (int q = 0; q < PACK_WPW; ++q)
        p[q] = probs[((size_t)(w0 + q) << 6) + lane];
    const float c0 = Cs[10], c1 = Cs[11], c2 = Cs[12], c3 = Cs[13], c4 = Cs[14];
#pragma unroll
    for (int q = 0; q < PACK_WPW; ++q) {
        int w = w0 + q;
        int i = w >> 6;                  // row
        int jbase = (w & 63) << 6;       // column of lane 0
        float pp = p[q];
        int k = (pp < c0) + (pp < c1) + (pp < c2) + (pp < c3) + (pp < c4);
        bool gE0 = (i == 0), gE1 = (i == HH - 1);
        bool jE0 = (jbase == 0) & (lane == 0);
        bool jE1 = (jbase == WW - 64) & (lane == 63);
        if (gE0 | gE1 | jE0 | jE1) {     // rare, divergent border fixup
            int ncnt = 4 - gE0 - gE1 - jE0 - jE1;
            const float* Cr = Cs + (ncnt - 2) * 5;
            k = (pp < Cr[0]) + (pp < Cr[1]) + (pp < Cr[2]) + (pp < Cr[3]) + (pp < Cr[4]);
        }
        u64 lb = __ballot(pp > 0.5f);
        u64 b0 = __ballot(k & 1);
        u64 b1 = __ballot(k & 2);
        u64 b2 = __ballot(k & 4);
        if (lane < 4) {
            u64 v = (lane == 0) ? lb : (lane == 1) ? b0 : (lane == 2) ? b1 : b2;
            Kp[4ull * w + lane] = v;
        }
    }
}

// Fused: (A) load packed region via b128 pairs (labels->LDS+regs, k-planes
// ->regs only), (B) half-sweeps with convergence early-exit, (C) expand.
__global__ __attribute__((amdgpu_flat_work_group_size(NTHR, NTHR),
                          amdgpu_waves_per_eu(4, 4)))
void fused_all(const u64* __restrict__ Kp, float* __restrict__ out) {
    __shared__ u64 SL[RWORDS];           // 19,840 B (labels only)
    __shared__ int chg[3];               // change flags, slot = sweep % 3

    const int tid = threadIdx.x;
    const int lane = tid & 63;
    const int tr = blockIdx.x >> 3;      // 0..31 tile row
    const int tc = blockIdx.x & 7;       // 0..7  tile col
    const int r0 = tr * TILE_R - HALO_R; // global row of region row 0
    const int wc0 = tc * 8 - 1;          // global word-col of region col 0

    if (tid < 3) chg[tid] = 0;

    // ---- Phase A: two ulonglong2 loads per word; k-planes in regs only ----
    const ulonglong2* Kp2 = (const ulonglong2*)Kp;
    u64 cur[WPT], k0[WPT], k1[WPT], k2[WPT], basem[WPT];
    int rr[WPT], cc[WPT];
#pragma unroll
    for (int m = 0; m < WPT; ++m) {
        int idx = tid + NTHR * m;
        int r = 0, c = 0;
        u64 l = 0, a = ~0ull, b = ~0ull, d = ~0ull;   // outside: label 0, k=7
        if (m < 2 || idx < RWORDS) {
            r = idx / REG_WC;
            c = idx - REG_WC * r;
            int g = r0 + r, wc = wc0 + c;
            if (g >= 0 && g < HH && wc >= 0 && wc < WPR) {
                size_t w = (size_t)g * WPR + wc;
                ulonglong2 x = Kp2[2 * w];       // (L, k0)
                ulonglong2 y = Kp2[2 * w + 1];   // (k1, k2)
                l = x.x; a = x.y; b = y.x; d = y.y;
            }
            SL[idx] = l;
        }
        cur[m] = l; k0[m] = a; k1[m] = b; k2[m] = d;
        rr[m] = r; cc[m] = c;
        basem[m] = ((r0 + r) & 1) ? 0xAAAAAAAAAAAAAAAAull
                                  : 0x5555555555555555ull;
    }
    __syncthreads();

    // ---- Phase B: in-place half-sweeps + convergence early-exit.
    // Two consecutive no-change half-sweeps => fixed point; later trapezoids
    // are subsets updated by the same rule -> identity -> break, bit-exact.
    // chg slots mod-3: clear of slot (s+1)%3 at sweep s is separated from its
    // last readers (sweep s-2) by the sweep-(s-1) barrier.
    int prevf = 1;
    for (int s = 0; s < NSWEEP; ++s) {
        if (tid == 0) chg[(s + 1) % 3] = 0;
        const u64 flip = (s & 1) ? ~0ull : 0ull;
        const int rlo = s + 1, rhi = REG_R - 1 - s;   // trapezoid bounds
        u64 chacc = 0;
#pragma unroll
        for (int m = 0; m < WPT; ++m) {
            int idx = tid + NTHR * m;
            int r = rr[m];
            if ((m < 2 || idx < RWORDS) && r >= rlo && r < rhi) {
                int c = cc[m];
                u64 center = cur[m];
                u64 up = SL[idx - REG_WC], dn = SL[idx + REG_WC];
                u64 pw = (c > 0) ? SL[idx - 1] : 0ull;
                u64 nw = (c < REG_WC - 1) ? SL[idx + 1] : 0ull;
                u64 lv = (center << 1) | (pw >> 63);
                u64 rv = (center >> 1) | (nw << 63);
                // bit-sliced ns = up+dn+lv+rv (planes n2:n1:n0)
                u64 sxy = up ^ dn, ca = up & dn;
                u64 txy = lv ^ rv, cb = lv & rv;
                u64 n0 = sxy ^ txy, cd = sxy & txy;
                u64 n1 = ca ^ cb ^ cd;
                u64 n2 = (ca & cb) | (cd & (ca ^ cb));
                // ge = (ns >= k), 3-bit unsigned compare
                u64 ge = (n2 & ~k2[m]) |
                         (~(n2 ^ k2[m]) & ((n1 & ~k1[m]) |
                                           (~(n1 ^ k1[m]) & (n0 | ~k0[m]))));
                u64 mask = basem[m] ^ flip;
                u64 nv = (ge & mask) | (center & ~mask);   // BFI
                chacc |= nv ^ center;
                cur[m] = nv;
                SL[idx] = nv;   // race-free: writes touch only parity-s bits
            }
        }
        if (__ballot(chacc != 0) != 0ull) {
            if (lane == 0) chg[s % 3] = 1;    // benign race, all write 1
        }
        __syncthreads();
        int curf = chg[s % 3];
        if (prevf == 0 && curf == 0) break;   // block-uniform decision
        prevf = curf;
    }

    // ---- Phase C: expand interior (128 rows x 512 bits) to float4 output ----
#pragma unroll 4
    for (int m = 0; m < 16; ++m) {
        int idx = tid + NTHR * m;          // 0..16383 float4s
        int ri = idx >> 7;                 // interior row 0..127
        int q = idx & 127;                 // float4 within row
        u64 word = SL[(HALO_R + ri) * REG_WC + 1 + (q >> 4)];
        unsigned bits = (unsigned)(word >> ((q & 15) * 4)) & 0xFu;
        float4 v;
        v.x = (float)(bits & 1u);
        v.y = (float)((bits >> 1) & 1u);
        v.z = (float)((bits >> 2) & 1u);
        v.w = (float)((bits >> 3) & 1u);
        int g = tr * TILE_R + ri;
        ((float4*)out)[(size_t)g * (WW / 4) + (wc0 + 1) * 16 + q] = v;
    }
}

// Host-side replica of the crossover computation (seed only; device verifies).
static bool h_decision(float p, int ncnt, int ns) {
    double pd = (double)p;
    double u1 = -log(pd + 1e-6);
    double u0 = -log1p(-(pd - 1e-6));
    return (u1 + 0.5 * (double)(ncnt - ns)) < (u0 + 0.5 * (double)ns);
}
static unsigned h_f2u(float f) { union { float f; unsigned u; } x; x.f = f; return x.u; }
static float h_u2f(unsigned u) { union { float f; unsigned u; } x; x.u = u; return x.f; }

extern "C" void kernel_launch(void* const* d_in, const int* in_sizes, int n_in,
                              void* d_out, int out_size, void* d_ws, size_t ws_size,
                              hipStream_t stream) {
    const float* probs = (const float*)d_in[0];
    float* out = (float*)d_out;
    u64* Kp = (u64*)d_ws;                // 8 MB AoS (L,k0,k1,k2)

    // Host: compute the 15 crossover constants (runs once at graph capture).
    C15 Ch;
    for (int t = 0; t < 15; ++t) {
        int ncnt = 2 + t / 5, ns = t % 5;
        unsigned lo = 0u, hi = 0x3F800000u;
        double T = 0.5 * (double)(2 * ns - ncnt);
        double eT = exp(T);
        double p0 = (1.0 + 1e-6 - 1e-6 * eT) / (1.0 + eT);
        float f0 = (float)p0;
        if (f0 < 0.0f) f0 = 0.0f;
        if (f0 > 1.0f) f0 = 1.0f;
        unsigned b0 = h_f2u(f0);
        unsigned l2 = (b0 > 64u) ? b0 - 64u : 0u;
        unsigned h2 = (b0 + 64u < 0x3F800000u) ? b0 + 64u : 0x3F800000u;
        if (!h_decision(h_u2f(l2), ncnt, ns)) lo = l2;
        if (h_decision(h_u2f(h2), ncnt, ns)) hi = h2;
        while (hi - lo > 1u) {
            unsigned mid = lo + (hi - lo) / 2u;
            if (h_decision(h_u2f(mid), ncnt, ns)) hi = mid; else lo = mid;
        }
        Ch.v[t] = h_u2f(hi);
    }

    pack_kernel<<<NWORDS / (PACK_WPW * 4), 256, 0, stream>>>(probs, Ch, Kp);
    fused_all<<<256, NTHR, 0, stream>>>(Kp, out);
}